// Round 3
// baseline (887.680 us; speedup 1.0000x reference)
//
#include <hip/hip_runtime.h>
#include <cstdint>
#include <cstddef>

// DenseCaps dynamic routing, MI355X — R3: recompute-u_hat design.
// B=256, R=2048, NC=10, OUT=16, IN=8, 3 routing iters.
//
// R2 post-mortem: 168 MB u_hat intermediate written once + read 4x dominated
// (5 x 168 MB at ~3.6 TB/s ~ 240 of 270 us). The einsum is only 671 M FMA
// (~8.5 us/pass at 157 TF fp32). R3 recomputes u_hat on the fly inside every
// routing pass: HBM working set shrinks to x (16 MB) + W (10 MB) + bB (21 MB),
// all L3-resident. All-fp32 compute (no fp16 storage error).
//
// Grid mapping: blockIdx = bt*128 + rt  (bt=b-tile 0..15, rt=r-tile 0..127).
// blockIdx%8 == rt%8 -> all 16 bt-blocks sharing a W r-slice land on the same
// XCD -> W slice (1.25 MB) is L2-resident per XCD.
// Block = 256 threads = 16 b-lanes x 16 n-lanes (10 active classes).
// Per-rt partial sums of s go to P[rt][B][160]; reduce_squash sums 128
// partials and applies squash (no atomics, no memset needed).
//
// bB aliases the c-output region of d_out (read+write same thread -> safe).

#define B_   256
#define R_   2048
#define NC_  10
#define TR_  16     // routes per block
#define NRT_ 128    // R_/TR_

__device__ __forceinline__ float rsum16(float x){
  x += __shfl_xor(x, 1, 16);
  x += __shfl_xor(x, 2, 16);
  x += __shfl_xor(x, 4, 16);
  x += __shfl_xor(x, 8, 16);
  return x;
}
__device__ __forceinline__ float rmax16(float x){
  x = fmaxf(x, __shfl_xor(x, 1, 16));
  x = fmaxf(x, __shfl_xor(x, 2, 16));
  x = fmaxf(x, __shfl_xor(x, 4, 16));
  x = fmaxf(x, __shfl_xor(x, 8, 16));
  return x;
}

// ---------- K0: c0 = softmax(b_in) over classes, per route ----------
__global__ __launch_bounds__(256) void c0_kernel(const float* __restrict__ b_in,
                                                 float* __restrict__ c0){
  int r = blockIdx.x * 256 + threadIdx.x;
  if (r >= R_) return;
  float t[NC_];
  float m = -1e30f;
  #pragma unroll
  for (int n = 0; n < NC_; ++n){ t[n] = b_in[r * NC_ + n]; m = fmaxf(m, t[n]); }
  float sum = 0.f;
  #pragma unroll
  for (int n = 0; n < NC_; ++n){ t[n] = __expf(t[n] - m); sum += t[n]; }
  float inv = 1.f / sum;
  #pragma unroll
  for (int n = 0; n < NC_; ++n) c0[r * NC_ + n] = t[n] * inv;
}

// ---------- fused routing pass with on-the-fly u_hat ----------
// MODE 0: c = c0 (no agreement step)
// MODE 1: bold = b_in, write bnew -> bB
// MODE 2: bold = bB,  write bnew -> bB
// MODE 3: bold = bB,  write c    -> bB (c output region)
template<int MODE>
__global__ __launch_bounds__(256) void pass_kernel(
    const float* __restrict__ x,     // [B][R][8]
    const float* __restrict__ W,     // [R][8][160]
    const float* __restrict__ c0,    // [R][NC]
    const float* __restrict__ b_in,  // [R][NC]
    float*       __restrict__ bB,    // [B][R][NC]
    const float* __restrict__ v,     // [B][160]
    float*       __restrict__ P)     // [NRT_][B][160] partial s
{
  const int bt = blockIdx.x >> 7;        // 0..15
  const int rt = blockIdx.x & 127;       // 0..127  (fixes XCD via blockIdx%8)
  const int n  = threadIdx.x & 15;       // class lane (10 active)
  const int bs = threadIdx.x >> 4;       // 0..15
  const int b  = bt * 16 + bs;
  const int nn = (n < NC_) ? n : (NC_ - 1);

  float vreg[16];
  if (MODE != 0){
    const float4* vp = (const float4*)(v + b * 160 + nn * 16);
    float4 v0 = vp[0], v1 = vp[1], v2 = vp[2], v3 = vp[3];
    vreg[0]=v0.x; vreg[1]=v0.y; vreg[2]=v0.z; vreg[3]=v0.w;
    vreg[4]=v1.x; vreg[5]=v1.y; vreg[6]=v1.z; vreg[7]=v1.w;
    vreg[8]=v2.x; vreg[9]=v2.y; vreg[10]=v2.z; vreg[11]=v2.w;
    vreg[12]=v3.x; vreg[13]=v3.y; vreg[14]=v3.z; vreg[15]=v3.w;
  }
  float acc[16];
  #pragma unroll
  for (int o = 0; o < 16; ++o) acc[o] = 0.f;

  const int r0 = rt * TR_;
  #pragma unroll 2
  for (int j = 0; j < TR_; ++j){
    const int r = r0 + j;
    // x[b,r,0..7]
    const float4* xp = (const float4*)(x + ((size_t)b * R_ + r) * 8);
    float4 xa = xp[0], xb = xp[1];
    float xr[8] = {xa.x, xa.y, xa.z, xa.w, xb.x, xb.y, xb.z, xb.w};
    // u[o] = sum_i x[i] * W[r,i,nn*16+o]   (lanes n>=10 duplicate n=9 -> merged loads)
    float u[16];
    #pragma unroll
    for (int o = 0; o < 16; ++o) u[o] = 0.f;
    const float4* Wp = (const float4*)(W + (size_t)r * 1280 + nn * 16);
    #pragma unroll
    for (int i = 0; i < 8; ++i){
      float4 w0 = Wp[i * 40 + 0];
      float4 w1 = Wp[i * 40 + 1];
      float4 w2 = Wp[i * 40 + 2];
      float4 w3 = Wp[i * 40 + 3];
      const float xi = xr[i];
      u[0]  = fmaf(xi, w0.x, u[0]);  u[1]  = fmaf(xi, w0.y, u[1]);
      u[2]  = fmaf(xi, w0.z, u[2]);  u[3]  = fmaf(xi, w0.w, u[3]);
      u[4]  = fmaf(xi, w1.x, u[4]);  u[5]  = fmaf(xi, w1.y, u[5]);
      u[6]  = fmaf(xi, w1.z, u[6]);  u[7]  = fmaf(xi, w1.w, u[7]);
      u[8]  = fmaf(xi, w2.x, u[8]);  u[9]  = fmaf(xi, w2.y, u[9]);
      u[10] = fmaf(xi, w2.z, u[10]); u[11] = fmaf(xi, w2.w, u[11]);
      u[12] = fmaf(xi, w3.x, u[12]); u[13] = fmaf(xi, w3.y, u[13]);
      u[14] = fmaf(xi, w3.z, u[14]); u[15] = fmaf(xi, w3.w, u[15]);
    }

    float c;
    if (MODE == 0){
      c = (n < NC_) ? c0[r * NC_ + nn] : 0.f;
    } else {
      float t = 0.f;
      #pragma unroll
      for (int o = 0; o < 16; ++o) t = fmaf(u[o], vreg[o], t);
      const size_t row = (size_t)b * R_ + r;
      float bold = (MODE == 1) ? b_in[r * NC_ + nn] : bB[row * NC_ + nn];
      float bnew = (n < NC_) ? (bold + t) : -1e30f;
      float m = rmax16(bnew);
      float e = __expf(bnew - m);            // idle lanes -> 0
      float sum = rsum16(e);
      c = e / sum;
      if (n < NC_){
        if (MODE == 3) bB[row * NC_ + n] = c;      // c output
        else           bB[row * NC_ + n] = bnew;   // logits for next iter
      }
    }
    #pragma unroll
    for (int o = 0; o < 16; ++o) acc[o] = fmaf(c, u[o], acc[o]);
  }

  // per-rt partial of s: P[rt][b][nn*16 + o]
  if (n < NC_){
    float4* Pp = (float4*)(P + ((size_t)rt * B_ + b) * 160 + n * 16);
    Pp[0] = make_float4(acc[0],  acc[1],  acc[2],  acc[3]);
    Pp[1] = make_float4(acc[4],  acc[5],  acc[6],  acc[7]);
    Pp[2] = make_float4(acc[8],  acc[9],  acc[10], acc[11]);
    Pp[3] = make_float4(acc[12], acc[13], acc[14], acc[15]);
  }
}

// ---------- reduce partials + squash ----------
__global__ __launch_bounds__(256) void reduce_squash(const float* __restrict__ P,
                                                     float* __restrict__ vout){
  int g = blockIdx.x * 256 + threadIdx.x;   // 0..40959; 16 lanes per (b,n) row
  float s0 = 0.f, s1 = 0.f, s2 = 0.f, s3 = 0.f;
  #pragma unroll 4
  for (int j = 0; j < NRT_; j += 4){
    s0 += P[(size_t)(j + 0) * 40960 + g];
    s1 += P[(size_t)(j + 1) * 40960 + g];
    s2 += P[(size_t)(j + 2) * 40960 + g];
    s3 += P[(size_t)(j + 3) * 40960 + g];
  }
  float sv = (s0 + s1) + (s2 + s3);
  float ss = rsum16(sv * sv);
  float f = sqrtf(ss) / (1.f + ss + 1e-8f);
  vout[g] = f * sv;
}

extern "C" void kernel_launch(void* const* d_in, const int* in_sizes, int n_in,
                              void* d_out, int out_size, void* d_ws, size_t ws_size,
                              hipStream_t stream){
  const float* x    = (const float*)d_in[0];   // [256,2048,8]
  const float* W    = (const float*)d_in[1];   // [2048,8,160]
  const float* b_in = (const float*)d_in[2];   // [2048,10]
  float* out   = (float*)d_out;
  float* out_v = out;                  // 40960 floats
  float* bB    = out + 40960;          // [B][R][NC] — doubles as c output

  char* w = (char*)d_ws;
  float* P  = (float*)w;                                  // 128*256*160*4 = 20.97 MB
  float* v  = (float*)(w + (size_t)NRT_ * B_ * 160 * 4);  // 163,840 B
  float* c0 = (float*)(w + (size_t)NRT_ * B_ * 160 * 4 + 163840);

  c0_kernel<<<8, 256, 0, stream>>>(b_in, c0);

  pass_kernel<0><<<2048, 256, 0, stream>>>(x, W, c0, b_in, bB, v, P);
  reduce_squash<<<160, 256, 0, stream>>>(P, v);
  pass_kernel<1><<<2048, 256, 0, stream>>>(x, W, c0, b_in, bB, v, P);
  reduce_squash<<<160, 256, 0, stream>>>(P, v);
  pass_kernel<2><<<2048, 256, 0, stream>>>(x, W, c0, b_in, bB, v, P);
  reduce_squash<<<160, 256, 0, stream>>>(P, v);
  pass_kernel<3><<<2048, 256, 0, stream>>>(x, W, c0, b_in, bB, v, P);
  reduce_squash<<<160, 256, 0, stream>>>(P, out_v);
}